// Round 8
// baseline (221.253 us; speedup 1.0000x reference)
//
#include <hip/hip_runtime.h>

typedef _Float16 half8  __attribute__((ext_vector_type(8)));
typedef _Float16 half4v __attribute__((ext_vector_type(4)));
typedef float    f32x4  __attribute__((ext_vector_type(4)));

#define ITER 16

__device__ __forceinline__ int swz(int row) {
    return ((row ^ (row >> 3)) & 15) << 4;   // 256B-row region, 16B granules
}

__device__ __forceinline__ half8 cvt_pair(f32x4 a, f32x4 b) {
    half8 h;
    h[0] = (_Float16)a[0]; h[1] = (_Float16)a[1]; h[2] = (_Float16)a[2]; h[3] = (_Float16)a[3];
    h[4] = (_Float16)b[0]; h[5] = (_Float16)b[1]; h[6] = (_Float16)b[2]; h[7] = (_Float16)b[3];
    return h;
}

// Persistent: grid 256 = 1 WG/CU, each WG runs 16 consecutive attention blocks.
// Cross-block software pipeline in REGISTERS (affordable at 2 waves/SIMD = 256 VGPR
// budget): while block i computes, K(i+1)+Q(i+1)+V(i) stream via inline-asm loads
// with counted vmcnt waits (never 0 in-loop) -> HBM always has >100KB outstanding/CU.
// LDS 64KB: [0,32K) K fp16 [128][256B] swz; [32K,64K) P fp16 [128][256B] swz.
// Two barriers per block: B1 (K staged), B2 (P staged).
__global__ __launch_bounds__(512, 2) void battn_kernel(
    const float* __restrict__ Q, const float* __restrict__ K,
    const float* __restrict__ V, float* __restrict__ O)
{
    __shared__ __align__(16) char smem[65536];
    const int tid  = threadIdx.x;
    const int lane = tid & 63;
    const int w    = tid >> 6;
    const int la   = lane & 15;
    const int u    = lane >> 4;

    const size_t base0 = (size_t)blockIdx.x * ITER * (128 * 128);

    f32x4 kreg[8];    // K(i) raw fp32 (prefetched)
    f32x4 qld[8];     // Q(i+1) raw
    float vld[32];    // V(i) raw
    half8 qfrag[4];   // Q(i) fragments

    // ---------------- prologue: Q(0) then K(0) ----------------
    {
        const float* qrow = Q + base0 + (w * 16 + la) * 128;
#pragma unroll
        for (int kk = 0; kk < 4; ++kk) {
            const float* p0 = qrow + kk * 32 + u * 8;
            asm volatile("global_load_dwordx4 %0, %1, off" : "=v"(qld[2 * kk])     : "v"(p0));
            asm volatile("global_load_dwordx4 %0, %1, off" : "=v"(qld[2 * kk + 1]) : "v"(p0 + 4));
        }
        const float* kptr = K + base0 + tid * 4;
#pragma unroll
        for (int it = 0; it < 8; ++it) {
            const float* p = kptr + it * 2048;
            asm volatile("global_load_dwordx4 %0, %1, off" : "=v"(kreg[it]) : "v"(p));
        }
    }
    asm volatile("s_waitcnt vmcnt(8)" ::: "memory");   // Q(0) done (K(0) may be in flight)
    __builtin_amdgcn_sched_barrier(0);
#pragma unroll
    for (int kk = 0; kk < 4; ++kk) qfrag[kk] = cvt_pair(qld[2 * kk], qld[2 * kk + 1]);
    asm volatile("s_waitcnt vmcnt(0)" ::: "memory");   // K(0) done
    __builtin_amdgcn_sched_barrier(0);

    for (int i = 0; i < ITER; ++i) {
        const size_t base  = base0 + (size_t)i * (128 * 128);
        const size_t nbase = base0 + (size_t)(i + 1 < ITER ? i + 1 : i) * (128 * 128);
        float* Ob = O + base;

        // ---- (a) stage K(i): kreg fp32 -> fp16 LDS, swizzled ----
#pragma unroll
        for (int it = 0; it < 8; ++it) {
            const int idx = it * 2048 + tid * 4;     // fp16 element index
            const int row = idx >> 7;
            const int col = idx & 127;
            half4v h;
            h[0] = (_Float16)kreg[it][0]; h[1] = (_Float16)kreg[it][1];
            h[2] = (_Float16)kreg[it][2]; h[3] = (_Float16)kreg[it][3];
            int byte = row * 256 + col * 2;
            byte ^= swz(row);
            *(half4v*)(smem + byte) = h;
        }

        // ---- (b) issue V(i): 32 asm dword loads (first in vmcnt order) ----
        {
            const float* vbase = V + base + w * 16 + la;
#pragma unroll
            for (int kk = 0; kk < 4; ++kk)
#pragma unroll
                for (int t2 = 0; t2 < 8; ++t2) {
                    const float* p = vbase + (kk * 32 + u * 8 + t2) * 128;
                    asm volatile("global_load_dword %0, %1, off"
                                 : "=v"(vld[kk * 8 + t2]) : "v"(p));
                }
        }
        // ---- (c) issue Q(i+1) 8, then K(i+1) 8 ----
        {
            const float* qrow = Q + nbase + (w * 16 + la) * 128;
#pragma unroll
            for (int kk = 0; kk < 4; ++kk) {
                const float* p0 = qrow + kk * 32 + u * 8;
                asm volatile("global_load_dwordx4 %0, %1, off" : "=v"(qld[2 * kk])     : "v"(p0));
                asm volatile("global_load_dwordx4 %0, %1, off" : "=v"(qld[2 * kk + 1]) : "v"(p0 + 4));
            }
            const float* kptr = K + nbase + tid * 4;
#pragma unroll
            for (int it = 0; it < 8; ++it) {
                const float* p = kptr + it * 2048;
                asm volatile("global_load_dwordx4 %0, %1, off" : "=v"(kreg[it]) : "v"(p));
            }
        }
        __builtin_amdgcn_sched_barrier(0);

        __syncthreads();                               // B1: K(i) staged

        // ---- (e) S = Q K^T (fp16 LDS path) ----
        f32x4 acc[8];
#pragma unroll
        for (int t = 0; t < 8; ++t) acc[t] = (f32x4){0.f, 0.f, 0.f, 0.f};
#pragma unroll
        for (int t = 0; t < 8; ++t) {
            const int row = t * 16 + la;
#pragma unroll
            for (int kk = 0; kk < 4; ++kk) {
                int byte = row * 256 + kk * 64 + u * 16;
                byte ^= swz(row);
                const half8 kf = *(const half8*)(smem + byte);
                acc[t] = __builtin_amdgcn_mfma_f32_16x16x32_f16(qfrag[kk], kf, acc[t], 0, 0, 0);
            }
        }
        // acc[t][r] = S[q-sub-row = 4u+r][col = 16t+la]

        // ---- (f) row softmax ----
        float inv[4];
#pragma unroll
        for (int r = 0; r < 4; ++r) {
            float m = acc[0][r];
#pragma unroll
            for (int t = 1; t < 8; ++t) m = fmaxf(m, acc[t][r]);
            m = fmaxf(m, __shfl_xor(m, 1));
            m = fmaxf(m, __shfl_xor(m, 2));
            m = fmaxf(m, __shfl_xor(m, 4));
            m = fmaxf(m, __shfl_xor(m, 8));
            float s = 0.f;
#pragma unroll
            for (int t = 0; t < 8; ++t) {
                const float e = __expf(acc[t][r] - m);
                acc[t][r] = e;
                s += e;
            }
            s += __shfl_xor(s, 1);
            s += __shfl_xor(s, 2);
            s += __shfl_xor(s, 4);
            s += __shfl_xor(s, 8);
            inv[r] = 1.0f / s;
        }

        // ---- (h) P -> LDS (separate region; prev PV readers fenced by B1) ----
#pragma unroll
        for (int t = 0; t < 8; ++t) {
#pragma unroll
            for (int r = 0; r < 4; ++r) {
                const int q   = w * 16 + u * 4 + r;
                const int col = t * 16 + la;
                int byte = 32768 + q * 256 + col * 2;
                byte ^= swz(q & 15);
                *(_Float16*)(smem + byte) = (_Float16)(acc[t][r] * inv[r]);
            }
        }
        __syncthreads();                               // B2: P staged

        // ---- (j) V(i) ready: vmcnt(16) leaves Q(i+1)8 + K(i+1)8 in flight ----
        asm volatile("s_waitcnt vmcnt(16)" ::: "memory");
        __builtin_amdgcn_sched_barrier(0);
        half8 vfrag[4];
#pragma unroll
        for (int kk = 0; kk < 4; ++kk)
#pragma unroll
            for (int t2 = 0; t2 < 8; ++t2)
                vfrag[kk][t2] = (_Float16)vld[kk * 8 + t2];

        // ---- (k) O^T = V^T P^T, store per q-tile (8 stores, after K in vmcnt order) ----
#pragma unroll
        for (int qt = 0; qt < 8; ++qt) {
            half8 pb[4];
#pragma unroll
            for (int kk = 0; kk < 4; ++kk) {
                int byte = 32768 + (qt * 16 + la) * 256 + kk * 64 + u * 16;
                byte ^= swz(la);
                pb[kk] = *(const half8*)(smem + byte);
            }
            f32x4 oa = (f32x4){0.f, 0.f, 0.f, 0.f};
#pragma unroll
            for (int kk = 0; kk < 4; ++kk)
                oa = __builtin_amdgcn_mfma_f32_16x16x32_f16(vfrag[kk], pb[kk], oa, 0, 0, 0);
            *(float4*)(Ob + (qt * 16 + la) * 128 + w * 16 + u * 4) =
                make_float4(oa[0], oa[1], oa[2], oa[3]);
        }

        // ---- (l) Q(i+1) ready: vmcnt(16) leaves K8 + stores8 ----
        asm volatile("s_waitcnt vmcnt(16)" ::: "memory");
        __builtin_amdgcn_sched_barrier(0);
#pragma unroll
        for (int kk = 0; kk < 4; ++kk) qfrag[kk] = cvt_pair(qld[2 * kk], qld[2 * kk + 1]);

        // ---- (m) K(i+1) ready: vmcnt(8) leaves only this iter's 8 O-stores ----
        asm volatile("s_waitcnt vmcnt(8)" ::: "memory");
        __builtin_amdgcn_sched_barrier(0);
    }
}

extern "C" void kernel_launch(void* const* d_in, const int* in_sizes, int n_in,
                              void* d_out, int out_size, void* d_ws, size_t ws_size,
                              hipStream_t stream) {
    const float* q = (const float*)d_in[0];
    const float* k = (const float*)d_in[1];
    const float* v = (const float*)d_in[2];
    float* o = (float*)d_out;
    const int nblocks = in_sizes[0] / (128 * 128);   // 4096
    const int nwg = nblocks / ITER;                  // 256 = 1 WG/CU, persistent
    battn_kernel<<<dim3(nwg), dim3(512), 0, stream>>>(q, k, v, o);
}

// Round 9
// 209.581 us; speedup vs baseline: 1.0557x; 1.0557x over previous
//
#include <hip/hip_runtime.h>

typedef _Float16 half8  __attribute__((ext_vector_type(8)));
typedef _Float16 half4v __attribute__((ext_vector_type(4)));
typedef _Float16 half2v __attribute__((ext_vector_type(2)));
typedef float    f32x4  __attribute__((ext_vector_type(4)));

__device__ __forceinline__ int swz(int row) {
    return ((row ^ (row >> 3)) & 15) << 4;   // 256B-row region, 16B granules
}

// One WG = one (b,h,n) 128x128 attention block. 8 waves; wave w owns q-rows
// [16w,16w+16) for the ENTIRE pipeline (QK^T, softmax, PV) via swapped-operand
// QK^T: acc = mfma(A=K, B=Q) gives S^T, so each lane holds its own q-row's
// scores -> softmax is 2 shuffles, and P stays IN REGISTERS (64-shuffle
// redistribution to the PV B-fragment layout). No P LDS round-trip.
// LDS 64KB: [0,32K) K fp16 [128][256B] swz; [32K,64K) Vt fp16 [128 d][256B] swz.
// ONE barrier per block (after K+Vt staging).
__global__ __launch_bounds__(512, 4) void battn_kernel(
    const float* __restrict__ Q, const float* __restrict__ K,
    const float* __restrict__ V, float* __restrict__ O)
{
    __shared__ __align__(16) char smem[65536];
    const int tid  = threadIdx.x;
    const int lane = tid & 63;
    const int w    = tid >> 6;
    const int la   = lane & 15;
    const int u    = lane >> 4;
    const size_t base = (size_t)blockIdx.x * (128 * 128);

    const float* Qb = Q + base;
    const float* Kb = K + base;
    const float* Vb = V + base;
    float*       Ob = O + base;

    // ---------------- staging: K, V, Q loads ----------------
    float4 kreg[8];
#pragma unroll
    for (int it = 0; it < 8; ++it)
        kreg[it] = *(const float4*)(Kb + it * 2048 + tid * 4);

    float4 vreg[2][4];                              // rows j0,j0+1 x cols d0..d0+7
#pragma unroll
    for (int it = 0; it < 2; ++it) {
        const int tau = it * 512 + tid;
        const int d0 = (tau & 15) * 8;
        const int j0 = (tau >> 4) * 2;
        vreg[it][0] = *(const float4*)(Vb + j0 * 128 + d0);
        vreg[it][1] = *(const float4*)(Vb + j0 * 128 + d0 + 4);
        vreg[it][2] = *(const float4*)(Vb + (j0 + 1) * 128 + d0);
        vreg[it][3] = *(const float4*)(Vb + (j0 + 1) * 128 + d0 + 4);
    }
    half8 qfrag[4];
    {
        const float* qrow = Qb + (w * 16 + la) * 128;
#pragma unroll
        for (int kk = 0; kk < 4; ++kk) {
            const float4 a = *(const float4*)(qrow + kk * 32 + u * 8);
            const float4 b = *(const float4*)(qrow + kk * 32 + u * 8 + 4);
            qfrag[kk][0] = (_Float16)a.x; qfrag[kk][1] = (_Float16)a.y;
            qfrag[kk][2] = (_Float16)a.z; qfrag[kk][3] = (_Float16)a.w;
            qfrag[kk][4] = (_Float16)b.x; qfrag[kk][5] = (_Float16)b.y;
            qfrag[kk][6] = (_Float16)b.z; qfrag[kk][7] = (_Float16)b.w;
        }
    }
    // K -> LDS fp16 row-major swizzled
#pragma unroll
    for (int it = 0; it < 8; ++it) {
        const int idx = it * 2048 + tid * 4;
        const int row = idx >> 7;
        const int col = idx & 127;
        half4v h;
        h[0] = (_Float16)kreg[it].x; h[1] = (_Float16)kreg[it].y;
        h[2] = (_Float16)kreg[it].z; h[3] = (_Float16)kreg[it].w;
        int byte = row * 256 + col * 2;
        byte ^= swz(row);
        *(half4v*)(smem + byte) = h;
    }
    // V -> LDS transposed (Vt[d][j]) swizzled
#pragma unroll
    for (int it = 0; it < 2; ++it) {
        const int tau = it * 512 + tid;
        const int d0 = (tau & 15) * 8;
        const int j0 = (tau >> 4) * 2;
        const float r0[8] = {vreg[it][0].x, vreg[it][0].y, vreg[it][0].z, vreg[it][0].w,
                             vreg[it][1].x, vreg[it][1].y, vreg[it][1].z, vreg[it][1].w};
        const float r1[8] = {vreg[it][2].x, vreg[it][2].y, vreg[it][2].z, vreg[it][2].w,
                             vreg[it][3].x, vreg[it][3].y, vreg[it][3].z, vreg[it][3].w};
#pragma unroll
        for (int i = 0; i < 8; ++i) {
            half2v h;
            h[0] = (_Float16)r0[i];
            h[1] = (_Float16)r1[i];
            const int row = d0 + i;                 // Vt row = d
            int byte = 32768 + row * 256 + j0 * 2;
            byte ^= swz(row);
            *(half2v*)(smem + byte) = h;
        }
    }
    __syncthreads();                                // the ONLY barrier

    // ---------------- S^T = K Q^T : A=K rows, B=Q ----------------
    // acc[jt][r] = S[q = 16w+la][j = 16jt + 4u + r]  (lane owns its q-row)
    f32x4 acc[8];
#pragma unroll
    for (int t = 0; t < 8; ++t) acc[t] = (f32x4){0.f, 0.f, 0.f, 0.f};
#pragma unroll
    for (int t = 0; t < 8; ++t) {
#pragma unroll
        for (int kk = 0; kk < 4; ++kk) {
            const int row = t * 16 + la;            // K row = j
            int byte = row * 256 + kk * 64 + u * 16;
            byte ^= swz(row);
            const half8 kf = *(const half8*)(smem + byte);
            acc[t] = __builtin_amdgcn_mfma_f32_16x16x32_f16(kf, qfrag[kk], acc[t], 0, 0, 0);
        }
    }

    // ---------------- softmax: in-lane over 32 + cross-u (2 shuffles) ----------------
    float m = acc[0][0];
#pragma unroll
    for (int t = 0; t < 8; ++t)
#pragma unroll
        for (int r = 0; r < 4; ++r) m = fmaxf(m, acc[t][r]);
    m = fmaxf(m, __shfl_xor(m, 16));
    m = fmaxf(m, __shfl_xor(m, 32));
    float s = 0.f;
#pragma unroll
    for (int t = 0; t < 8; ++t)
#pragma unroll
        for (int r = 0; r < 4; ++r) {
            const float e = __expf(acc[t][r] - m);
            acc[t][r] = e;
            s += e;
        }
    s += __shfl_xor(s, 16);
    s += __shfl_xor(s, 32);
    const float inv = 1.0f / s;
#pragma unroll
    for (int t = 0; t < 8; ++t)
#pragma unroll
        for (int r = 0; r < 4; ++r) acc[t][r] *= inv;

    // ---------------- in-register P redistribution -> PV B-fragments ----------------
    // pa[kk][i] = P[q][32kk + 8u + i]; source lane = la + 32(u&1) + 16(i>>2),
    // source reg = acc[2kk + (u>>1)][i&3]   (all sent indices compile-time).
    const int srcA = la + 32 * (u & 1);
    const int srcB = srcA + 16;
    const int hi   = u >> 1;
    half8 pa[4];
#pragma unroll
    for (int kk = 0; kk < 4; ++kk) {
#pragma unroll
        for (int r = 0; r < 4; ++r) {
            const float sA0 = __shfl(acc[2 * kk][r],     srcA);
            const float sA1 = __shfl(acc[2 * kk + 1][r], srcA);
            const float sB0 = __shfl(acc[2 * kk][r],     srcB);
            const float sB1 = __shfl(acc[2 * kk + 1][r], srcB);
            pa[kk][r]     = (_Float16)(hi ? sA1 : sA0);
            pa[kk][4 + r] = (_Float16)(hi ? sB1 : sB0);
        }
    }

    // ---------------- O^T = Vt * P^T : A = Vt rows (m=d), B = pa (n=q) ----------------
#pragma unroll
    for (int dt = 0; dt < 8; ++dt) {
        f32x4 oa = (f32x4){0.f, 0.f, 0.f, 0.f};
#pragma unroll
        for (int kk = 0; kk < 4; ++kk) {
            const int row = dt * 16 + la;           // Vt row = d
            int byte = 32768 + row * 256 + kk * 64 + u * 16;
            byte ^= swz(row);
            const half8 vf = *(const half8*)(smem + byte);
            oa = __builtin_amdgcn_mfma_f32_16x16x32_f16(vf, pa[kk], oa, 0, 0, 0);
        }
        // lane holds O[q = 16w+la][d = dt*16 + 4u + r] -> contiguous float4
        *(float4*)(Ob + (w * 16 + la) * 128 + dt * 16 + u * 4) =
            make_float4(oa[0], oa[1], oa[2], oa[3]);
    }
}

extern "C" void kernel_launch(void* const* d_in, const int* in_sizes, int n_in,
                              void* d_out, int out_size, void* d_ws, size_t ws_size,
                              hipStream_t stream) {
    const float* q = (const float*)d_in[0];
    const float* k = (const float*)d_in[1];
    const float* v = (const float*)d_in[2];
    float* o = (float*)d_out;
    const int nblocks = in_sizes[0] / (128 * 128);   // 4096
    battn_kernel<<<dim3(nblocks), dim3(512), 0, stream>>>(q, k, v, o);
}